// Round 7
// baseline (367.413 us; speedup 1.0000x reference)
//
#include <hip/hip_runtime.h>

// CIN_51539607712 — R9: R5 structure (4-way K-split, 16 waves, 4 waves/SIMD)
// with the VGPR-cap artifact fixed: __launch_bounds__(1024, 1) (on this
// toolchain the 2nd arg acts CUDA-style min-blocks/CU; R5's (1024,4) forced
// VGPR=64 -> 230 MB scratch spill and buried the experiment).
// Per-wave iteration IDENTICAL to R4 (24 MFMA, 4 ds_read_b128, private 4 KB
// W dbuf, depth-2 counted-vmcnt pipeline, barrier-free): R6/R8 showed that
// shrinking per-wave tiles or sharing W via barriers regresses. W/xt traffic
// unchanged vs R4 (grid 256 x 64-row blocks, each streams W once).
// out[r,n] = sum_h xl[r,h] * Y_h[r,n],  Y_h[r,n] = sum_m x0[r,m] W[h*32+m,n].
// Y via 3 bf16 MFMAs (x0h*wh + x0h*wl + x0l*wh), then fp32 fma by xl (exact).
// 16 waves: kh = w&3 (K quarter), nq = w>>2 (N quarter). LDS 128 KB dynamic:
// 16 regions x 2048 u32 (per-wave 4 KB dbuf x2; reused as partial-acc dump).
// History: R4 null (latency), R6 neg (tile shrink), R7 null (LDS latency),
// R8 neg (shared-W + barriers). Occupancy-at-constant-shape is the one
// untested lever.

typedef unsigned int u32;
typedef __attribute__((ext_vector_type(8))) short short8;
typedef __attribute__((ext_vector_type(4))) float f32x4;
typedef __attribute__((ext_vector_type(4))) u32 u32x4;

#define R_TOTAL 16384
#define GLOBAL_AS __attribute__((address_space(1)))
#define LDS_AS __attribute__((address_space(3)))

union PackU { u32 u[4]; short8 s; };
union PackB { u32x4 v; short8 s; };

// pack bf16(a) into low half, bf16(b) into high half (truncation)
__device__ __forceinline__ u32 pack_trunc(float a, float b) {
  return __builtin_amdgcn_perm(__float_as_uint(b), __float_as_uint(a), 0x07060302u);
}

// ---------------- fused prep kernel ----------------
// blocks 0..127: build X0T[m][b*16+d] = in[b][m][d]  (32 x 16384)
// blocks 128..255 / 256..767 / 768..1279: swizzle W0 / W1 / W2.
__device__ __forceinline__ void build_x0t_body(const float* __restrict__ in,
                                               float* __restrict__ x0t,
                                               int bid, int tid, float* t) {
  const int b0 = bid * 8;
  #pragma unroll
  for (int rep = 0; rep < 4; ++rep) {
    int idx = tid + rep * 256;
    *(float4*)&t[idx * 4] = *(const float4*)&in[(size_t)b0 * 512 + idx * 4];
  }
  __syncthreads();
  #pragma unroll
  for (int rep = 0; rep < 4; ++rep) {
    int idx = tid + rep * 256;     // 0..1023: m(32) x bl(8) x dq(4)
    int m = idx >> 5, rem = idx & 31;
    int bl = rem >> 2, dq = rem & 3;
    *(float4*)&x0t[(size_t)m * R_TOTAL + (b0 + bl) * 16 + dq * 4] =
        *(const float4*)&t[bl * 512 + m * 16 + dq * 4];
  }
}

// Block (t = bid>>2, nq = bid&3). Image: [nl 0..31][p 0..7] 16B blocks; position
// p holds logical block l = p ^ (nl&7); l = h*4+q -> split-part h of
// W[t*32+q*8+j][nq*32+nl], j pairs packed (even=lo half, odd=hi half).
__device__ __forceinline__ void swizzle_body(const float* __restrict__ W,
                                             u32* __restrict__ wt,
                                             int bid, int tid, float* wl) {
  const int t = bid >> 2, nq = bid & 3;
  {
    int kk = tid >> 3, c4 = tid & 7;
    float4 v = *(const float4*)&W[(size_t)(t * 32 + kk) * 128 + nq * 32 + c4 * 4];
    wl[kk * 33 + c4 * 4 + 0] = v.x;
    wl[kk * 33 + c4 * 4 + 1] = v.y;
    wl[kk * 33 + c4 * 4 + 2] = v.z;
    wl[kk * 33 + c4 * 4 + 3] = v.w;
  }
  __syncthreads();
  {
    int nl = tid >> 3, p = tid & 7;
    int l = p ^ (nl & 7);
    int h = l >> 2, q = l & 3;
    u32 o[4];
    #pragma unroll
    for (int jj = 0; jj < 4; ++jj) {
      float v0 = wl[(q * 8 + 2 * jj + 0) * 33 + nl];
      float v1 = wl[(q * 8 + 2 * jj + 1) * 33 + nl];
      if (h == 1) {
        v0 -= __uint_as_float(__float_as_uint(v0) & 0xffff0000u);
        v1 -= __uint_as_float(__float_as_uint(v1) & 0xffff0000u);
      }
      o[jj] = pack_trunc(v0, v1);
    }
    *(u32x4*)(wt + (size_t)(t * 4 + nq) * 1024 + nl * 32 + p * 4) =
        u32x4{o[0], o[1], o[2], o[3]};
  }
}

__global__ __launch_bounds__(256) void prep_all(
    const float* __restrict__ in, float* __restrict__ x0t,
    const float* __restrict__ W0, u32* __restrict__ wt0,
    const float* __restrict__ W1, u32* __restrict__ wt1,
    const float* __restrict__ W2, u32* __restrict__ wt2) {
  __shared__ float sh[4096];
  const int b = blockIdx.x, tid = threadIdx.x;
  if (b < 128)      build_x0t_body(in, x0t, b, tid, sh);
  else if (b < 256) swizzle_body(W0, wt0, b - 128, tid, sh);
  else if (b < 768) swizzle_body(W1, wt1, b - 256, tid, sh);
  else              swizzle_body(W2, wt2, b - 768, tid, sh);
}

// ---------------- per-wave tile staging: 4096 B via global_load_lds ----------
__device__ __forceinline__ void stage4k(const u32* g, u32* l, int lane) {
  const GLOBAL_AS u32* gp = (const GLOBAL_AS u32*)g;
  LDS_AS u32* lp = (LDS_AS u32*)l;
  #pragma unroll
  for (int i = 0; i < 4; ++i)
    __builtin_amdgcn_global_load_lds(gp + i * 256 + lane * 4, lp + i * 256, 16, 0, 0);
}

// K-loop iteration. WAITIMM: 0x0F78 = vmcnt(8) (group I done, group I+1's 8
// vmem ops in flight), 0x0F70 = vmcnt(0) (peeled last iter). SLOT = I&1.
// Group issue order is always [stage4k(4), xl(4)] -> 8 vmem ops per group.
#define KITER(I, SLOT, WAITIMM, DO_STAGE)                                      \
  {                                                                            \
    __builtin_amdgcn_s_waitcnt(WAITIMM);                                       \
    __builtin_amdgcn_sched_barrier(0);                                         \
    f32x4 xlc[4];                                                              \
    xlc[0] = xn[SLOT][0]; xlc[1] = xn[SLOT][1];                                \
    xlc[2] = xn[SLOT][2]; xlc[3] = xn[SLOT][3];                                \
    const u32* buf = mybuf + (SLOT) * 1024;                                    \
    PackB bh0, bl0, bh1, bl1;                                                  \
    {                                                                          \
      const u32* row0 = buf + ln15 * 32;                                       \
      bh0.v = *(const u32x4*)(row0 + ((q ^ sw) * 4));                          \
      bl0.v = *(const u32x4*)(row0 + (((4 + q) ^ sw) * 4));                    \
      const u32* row1 = buf + (16 + ln15) * 32;                                \
      bh1.v = *(const u32x4*)(row1 + ((q ^ sw) * 4));                          \
      bl1.v = *(const u32x4*)(row1 + (((4 + q) ^ sw) * 4));                    \
    }                                                                          \
    asm volatile("s_waitcnt lgkmcnt(0)" ::: "memory");                         \
    __builtin_amdgcn_sched_barrier(0);                                         \
    if (DO_STAGE) {                                                            \
      stage4k(wt + (size_t)((t0 + (I) + 2) * 4 + nq) * 1024,                   \
              mybuf + (SLOT) * 1024, lane);                                    \
      const float* xp = xt + (size_t)(t0 + (I) + 2) * R_TOTAL + r0;            \
      xn[SLOT][0] = *(const f32x4*)(xp + 0 + q * 4);                           \
      xn[SLOT][1] = *(const f32x4*)(xp + 16 + q * 4);                          \
      xn[SLOT][2] = *(const f32x4*)(xp + 32 + q * 4);                          \
      xn[SLOT][3] = *(const f32x4*)(xp + 48 + q * 4);                          \
    }                                                                          \
    __builtin_amdgcn_sched_barrier(0);                                         \
    __builtin_amdgcn_s_setprio(1);                                             \
    _Pragma("unroll")                                                          \
    for (int f = 0; f < 4; ++f) {                                              \
      f32x4 Y = __builtin_amdgcn_mfma_f32_16x16x32_bf16(Ah[f].s, bh0.s, zero4, 0, 0, 0); \
      Y = __builtin_amdgcn_mfma_f32_16x16x32_bf16(Ah[f].s, bl0.s, Y, 0, 0, 0); \
      Y = __builtin_amdgcn_mfma_f32_16x16x32_bf16(Al[f].s, bh0.s, Y, 0, 0, 0); \
      acc[f][0] += xlc[f] * Y;                                                 \
    }                                                                          \
    _Pragma("unroll")                                                          \
    for (int f = 0; f < 4; ++f) {                                              \
      f32x4 Y = __builtin_amdgcn_mfma_f32_16x16x32_bf16(Ah[f].s, bh1.s, zero4, 0, 0, 0); \
      Y = __builtin_amdgcn_mfma_f32_16x16x32_bf16(Ah[f].s, bl1.s, Y, 0, 0, 0); \
      Y = __builtin_amdgcn_mfma_f32_16x16x32_bf16(Al[f].s, bh1.s, Y, 0, 0, 0); \
      acc[f][1] += xlc[f] * Y;                                                 \
    }                                                                          \
    __builtin_amdgcn_s_setprio(0);                                             \
    __builtin_amdgcn_sched_barrier(0);                                         \
  }

// ---------------- main layer kernel ----------------
// 16 waves: kh = w&3 (K quarter), nq = w>>2 (N quarter). LDS 128 KB dynamic:
// 16 regions x 2048 u32. __launch_bounds__(1024, 1): one 16-wave block/CU,
// VGPR cap 128 (4 waves/SIMD), no spill.
template <int NT, bool RELU, bool STORE_X>
__global__ __launch_bounds__(1024, 1) void layer_mfma(
    const float* __restrict__ xt,    // NT x R (transposed prev activation)
    const float* __restrict__ x0t,   // 32 x R
    const u32* __restrict__ wt,      // NT*4 quarter images (1024 u32 each)
    const float* __restrict__ bias,  // 128
    float* __restrict__ xoutT,       // 128 x R (if STORE_X)
    float* __restrict__ osum)        // d_out + layer offset, stride 384
{
  constexpr int HT = NT / 4;
  static_assert((HT & 1) == 0 && HT >= 4, "pair-loop needs even HT >= 4");
  extern __shared__ u32 smem[];      // 128 KB: 16 waves x 2048 u32

  const int tid = threadIdx.x;
  const int w = tid >> 6, lane = tid & 63;
  const int ln15 = lane & 15, q = lane >> 4;
  const int kh = w & 3, nq = w >> 2;
  const int r0 = blockIdx.x * 64;
  const int sw = ln15 & 7;
  u32* mybuf = smem + w * 2048;

  // ---- loop-invariant A fragments: split x0 rows (A[i=ln15][k=q*8+j]) ----
  PackU Ah[4], Al[4];
  #pragma unroll
  for (int f = 0; f < 4; ++f) {
    const int rbase = r0 + f * 16 + ln15;
    float e[8];
    #pragma unroll
    for (int j = 0; j < 8; ++j) e[j] = x0t[(size_t)(q * 8 + j) * R_TOTAL + rbase];
    #pragma unroll
    for (int jj = 0; jj < 4; ++jj) {
      float z0 = e[2 * jj], z1 = e[2 * jj + 1];
      Ah[f].u[jj] = pack_trunc(z0, z1);
      float h0 = __uint_as_float(__float_as_uint(z0) & 0xffff0000u);
      float h1 = __uint_as_float(__float_as_uint(z1) & 0xffff0000u);
      Al[f].u[jj] = pack_trunc(z0 - h0, z1 - h1);
    }
  }

  f32x4 acc[4][2];
  #pragma unroll
  for (int f = 0; f < 4; ++f)
    #pragma unroll
    for (int c = 0; c < 2; ++c) acc[f][c] = f32x4{0.f, 0.f, 0.f, 0.f};
  const f32x4 zero4 = {0.f, 0.f, 0.f, 0.f};

  const int t0 = kh * HT;

  // ---- prologue: 2-deep prefetch (groups 0 and 1), issue order stage,xl ----
  f32x4 xn[2][4];
  stage4k(wt + (size_t)(t0 * 4 + nq) * 1024, mybuf, lane);
  {
    const float* xp = xt + (size_t)t0 * R_TOTAL + r0;
    xn[0][0] = *(const f32x4*)(xp + 0 + q * 4);
    xn[0][1] = *(const f32x4*)(xp + 16 + q * 4);
    xn[0][2] = *(const f32x4*)(xp + 32 + q * 4);
    xn[0][3] = *(const f32x4*)(xp + 48 + q * 4);
  }
  stage4k(wt + (size_t)((t0 + 1) * 4 + nq) * 1024, mybuf + 1024, lane);
  {
    const float* xp = xt + (size_t)(t0 + 1) * R_TOTAL + r0;
    xn[1][0] = *(const f32x4*)(xp + 0 + q * 4);
    xn[1][1] = *(const f32x4*)(xp + 16 + q * 4);
    xn[1][2] = *(const f32x4*)(xp + 32 + q * 4);
    xn[1][3] = *(const f32x4*)(xp + 48 + q * 4);
  }
  __builtin_amdgcn_sched_barrier(0);

  // ---- steady state: every in-loop iter stages (i+2), waits vmcnt(8) ----
  for (int i = 0; i < HT - 2; i += 2) {
    KITER(i, 0, 0x0F78, 1);
    KITER(i + 1, 1, 0x0F78, 1);
  }
  // ---- peeled last pair: no staging; final iter drains to vmcnt(0) ----
  KITER(HT - 2, 0, 0x0F78, 0);
  KITER(HT - 1, 1, 0x0F70, 0);

  // ---------------- epilogue: 4-way partial reduction ----------------
  __syncthreads();                  // K-loop LDS regions now reusable
  if (kh != 0) {                    // dump partial acc into own region (8 KB)
    u32* reg = mybuf;
    #pragma unroll
    for (int f = 0; f < 4; ++f)
      #pragma unroll
      for (int c = 0; c < 2; ++c)
        *(f32x4*)(reg + ((size_t)(f * 2 + c) * 64 + lane) * 4) = acc[f][c];
  }
  __syncthreads();
  if (kh == 0) {
    float bs[2];
    #pragma unroll
    for (int c = 0; c < 2; ++c) bs[c] = bias[nq * 32 + c * 16 + ln15];

    f32x4 vv[4][2];
    #pragma unroll
    for (int f = 0; f < 4; ++f) {
      #pragma unroll
      for (int c = 0; c < 2; ++c) {
        f32x4 v = acc[f][c];
        #pragma unroll
        for (int p = 1; p < 4; ++p) {     // partners w+1..w+3 (kh=1..3, same nq)
          const u32* reg = smem + (size_t)(w + p) * 2048;
          v += *(const f32x4*)(reg + ((size_t)(f * 2 + c) * 64 + lane) * 4);
        }
        v.x += bs[c]; v.y += bs[c]; v.z += bs[c]; v.w += bs[c];
        if (RELU) {
          v.x = fmaxf(v.x, 0.f); v.y = fmaxf(v.y, 0.f);
          v.z = fmaxf(v.z, 0.f); v.w = fmaxf(v.w, 0.f);
        }
        vv[f][c] = v;
        float s = v.x + v.y + v.z + v.w;       // 4 rows of batch (r0>>4)+f
        s += __shfl_xor(s, 16, 64);
        s += __shfl_xor(s, 32, 64);
        if (q == 0)
          osum[(size_t)((r0 >> 4) + f) * 384 + nq * 32 + c * 16 + ln15] = s;
      }
    }

    if (STORE_X) {
      // transpose via own LDS region, then 64B-contiguous stores to XT.
      u32* myreg = mybuf;
      #pragma unroll
      for (int f = 0; f < 4; ++f)
        #pragma unroll
        for (int c = 0; c < 2; ++c)
          *(f32x4*)(myreg + ((size_t)(f * 2 + c) * 64 + lane) * 4) = vv[f][c];
      // element (r_local, lcol): frag (f=r>>4, c=lcol>>4), lane q=(r>>2)&3,
      // ln15=lcol&15, comp rr=r&3. Round (c,s): lane -> col=c*16+(lane>>2),
      // r_local = s*16 + (lane&3)*4.
      #pragma unroll
      for (int c = 0; c < 2; ++c) {
        #pragma unroll
        for (int s = 0; s < 4; ++s) {
          f32x4 vr = *(const f32x4*)(myreg +
              ((size_t)(s * 2 + c) * 64 + (lane & 3) * 16 + (lane >> 2)) * 4);
          const int col = nq * 32 + c * 16 + (lane >> 2);
          *(f32x4*)&xoutT[(size_t)col * R_TOTAL + r0 + s * 16 + (lane & 3) * 4] = vr;
        }
      }
    }
  }
}

extern "C" void kernel_launch(void* const* d_in, const int* in_sizes, int n_in,
                              void* d_out, int out_size, void* d_ws, size_t ws_size,
                              hipStream_t stream) {
  const float* in = (const float*)d_in[0];
  const float* W0 = (const float*)d_in[1];
  const float* b0 = (const float*)d_in[2];
  const float* W1 = (const float*)d_in[3];
  const float* b1 = (const float*)d_in[4];
  const float* W2 = (const float*)d_in[5];
  const float* b2 = (const float*)d_in[6];
  float* out = (float*)d_out;

  float* X0T = (float*)d_ws;                         // 32 x 16384   (2 MB)
  float* X1T = X0T + (size_t)32 * R_TOTAL;           // 128 x 16384  (8 MB)
  float* X2T = X1T + (size_t)128 * R_TOTAL;          // 128 x 16384  (8 MB)
  u32* Wt0 = (u32*)(X2T + (size_t)128 * R_TOTAL);    // 32*4*1024 u32  (0.5 MB)
  u32* Wt1 = Wt0 + (size_t)32 * 4 * 1024;            // 128*4*1024 u32 (2 MB)
  u32* Wt2 = Wt1 + (size_t)128 * 4 * 1024;           // 128*4*1024 u32 (2 MB)
  // total ws: 22.5 MB

  prep_all<<<1280, 256, 0, stream>>>(in, X0T, W0, Wt0, W1, Wt1, W2, Wt2);

  constexpr size_t kLds = 16 * 2048 * sizeof(u32);   // 128 KB dynamic LDS

  layer_mfma<32, true, true><<<256, 1024, kLds, stream>>>(X0T, X0T, Wt0, b0, X1T, out + 0);
  layer_mfma<128, true, true><<<256, 1024, kLds, stream>>>(X1T, X0T, Wt1, b1, X2T, out + 128);
  layer_mfma<128, false, false><<<256, 1024, kLds, stream>>>(X2T, X0T, Wt2, b2, nullptr, out + 256);
}

// Round 8
// 365.706 us; speedup vs baseline: 1.0047x; 1.0047x over previous
//
#include <hip/hip_runtime.h>

// CIN_51539607712 — R10: R9 structure (4-way K-split, 16 waves/block, 4
// waves/SIMD, per-wave iteration IDENTICAL to R4) with the register budget
// PINNED via __attribute__((amdgpu_waves_per_eu(4,4))).
// R5/R9 post-mortem: with a 1024-thr block + dynamic LDS, hipcc's allocator
// targets 8 waves/EU and squeezes to 64 VGPR -> 230 MB scratch spill;
// __launch_bounds__' 2nd arg is only a lower bound and cannot stop it.
// waves_per_eu(4,4) sets the occupancy target = exactly 4 waves/EU ->
// 128-VGPR budget; live state ~90 VGPR fits, no spill.
// out[r,n] = sum_h xl[r,h] * Y_h[r,n],  Y_h[r,n] = sum_m x0[r,m] W[h*32+m,n].
// Y via 3 bf16 MFMAs (x0h*wh + x0h*wl + x0l*wh), then fp32 fma by xl (exact).
// 16 waves: kh = w&3 (K quarter), nq = w>>2 (N quarter). LDS 128 KB dynamic:
// 16 regions x 2048 u32 (per-wave 4 KB dbuf x2; reused as partial-acc dump).
// History: R4 null (latency), R6 neg (tile shrink), R7 null (LDS latency),
// R8 neg (shared-W + barriers), R5/R9 buried by VGPR-64 spill artifact.

typedef unsigned int u32;
typedef __attribute__((ext_vector_type(8))) short short8;
typedef __attribute__((ext_vector_type(4))) float f32x4;
typedef __attribute__((ext_vector_type(4))) u32 u32x4;

#define R_TOTAL 16384
#define GLOBAL_AS __attribute__((address_space(1)))
#define LDS_AS __attribute__((address_space(3)))

union PackU { u32 u[4]; short8 s; };
union PackB { u32x4 v; short8 s; };

// pack bf16(a) into low half, bf16(b) into high half (truncation)
__device__ __forceinline__ u32 pack_trunc(float a, float b) {
  return __builtin_amdgcn_perm(__float_as_uint(b), __float_as_uint(a), 0x07060302u);
}

// ---------------- fused prep kernel ----------------
// blocks 0..127: build X0T[m][b*16+d] = in[b][m][d]  (32 x 16384)
// blocks 128..255 / 256..767 / 768..1279: swizzle W0 / W1 / W2.
__device__ __forceinline__ void build_x0t_body(const float* __restrict__ in,
                                               float* __restrict__ x0t,
                                               int bid, int tid, float* t) {
  const int b0 = bid * 8;
  #pragma unroll
  for (int rep = 0; rep < 4; ++rep) {
    int idx = tid + rep * 256;
    *(float4*)&t[idx * 4] = *(const float4*)&in[(size_t)b0 * 512 + idx * 4];
  }
  __syncthreads();
  #pragma unroll
  for (int rep = 0; rep < 4; ++rep) {
    int idx = tid + rep * 256;     // 0..1023: m(32) x bl(8) x dq(4)
    int m = idx >> 5, rem = idx & 31;
    int bl = rem >> 2, dq = rem & 3;
    *(float4*)&x0t[(size_t)m * R_TOTAL + (b0 + bl) * 16 + dq * 4] =
        *(const float4*)&t[bl * 512 + m * 16 + dq * 4];
  }
}

// Block (t = bid>>2, nq = bid&3). Image: [nl 0..31][p 0..7] 16B blocks; position
// p holds logical block l = p ^ (nl&7); l = h*4+q -> split-part h of
// W[t*32+q*8+j][nq*32+nl], j pairs packed (even=lo half, odd=hi half).
__device__ __forceinline__ void swizzle_body(const float* __restrict__ W,
                                             u32* __restrict__ wt,
                                             int bid, int tid, float* wl) {
  const int t = bid >> 2, nq = bid & 3;
  {
    int kk = tid >> 3, c4 = tid & 7;
    float4 v = *(const float4*)&W[(size_t)(t * 32 + kk) * 128 + nq * 32 + c4 * 4];
    wl[kk * 33 + c4 * 4 + 0] = v.x;
    wl[kk * 33 + c4 * 4 + 1] = v.y;
    wl[kk * 33 + c4 * 4 + 2] = v.z;
    wl[kk * 33 + c4 * 4 + 3] = v.w;
  }
  __syncthreads();
  {
    int nl = tid >> 3, p = tid & 7;
    int l = p ^ (nl & 7);
    int h = l >> 2, q = l & 3;
    u32 o[4];
    #pragma unroll
    for (int jj = 0; jj < 4; ++jj) {
      float v0 = wl[(q * 8 + 2 * jj + 0) * 33 + nl];
      float v1 = wl[(q * 8 + 2 * jj + 1) * 33 + nl];
      if (h == 1) {
        v0 -= __uint_as_float(__float_as_uint(v0) & 0xffff0000u);
        v1 -= __uint_as_float(__float_as_uint(v1) & 0xffff0000u);
      }
      o[jj] = pack_trunc(v0, v1);
    }
    *(u32x4*)(wt + (size_t)(t * 4 + nq) * 1024 + nl * 32 + p * 4) =
        u32x4{o[0], o[1], o[2], o[3]};
  }
}

__global__ __launch_bounds__(256) void prep_all(
    const float* __restrict__ in, float* __restrict__ x0t,
    const float* __restrict__ W0, u32* __restrict__ wt0,
    const float* __restrict__ W1, u32* __restrict__ wt1,
    const float* __restrict__ W2, u32* __restrict__ wt2) {
  __shared__ float sh[4096];
  const int b = blockIdx.x, tid = threadIdx.x;
  if (b < 128)      build_x0t_body(in, x0t, b, tid, sh);
  else if (b < 256) swizzle_body(W0, wt0, b - 128, tid, sh);
  else if (b < 768) swizzle_body(W1, wt1, b - 256, tid, sh);
  else              swizzle_body(W2, wt2, b - 768, tid, sh);
}

// ---------------- per-wave tile staging: 4096 B via global_load_lds ----------
__device__ __forceinline__ void stage4k(const u32* g, u32* l, int lane) {
  const GLOBAL_AS u32* gp = (const GLOBAL_AS u32*)g;
  LDS_AS u32* lp = (LDS_AS u32*)l;
  #pragma unroll
  for (int i = 0; i < 4; ++i)
    __builtin_amdgcn_global_load_lds(gp + i * 256 + lane * 4, lp + i * 256, 16, 0, 0);
}

// K-loop iteration. WAITIMM: 0x0F78 = vmcnt(8) (group I done, group I+1's 8
// vmem ops in flight), 0x0F70 = vmcnt(0) (peeled last iter). SLOT = I&1.
// Group issue order is always [stage4k(4), xl(4)] -> 8 vmem ops per group.
#define KITER(I, SLOT, WAITIMM, DO_STAGE)                                      \
  {                                                                            \
    __builtin_amdgcn_s_waitcnt(WAITIMM);                                       \
    __builtin_amdgcn_sched_barrier(0);                                         \
    f32x4 xlc[4];                                                              \
    xlc[0] = xn[SLOT][0]; xlc[1] = xn[SLOT][1];                                \
    xlc[2] = xn[SLOT][2]; xlc[3] = xn[SLOT][3];                                \
    const u32* buf = mybuf + (SLOT) * 1024;                                    \
    PackB bh0, bl0, bh1, bl1;                                                  \
    {                                                                          \
      const u32* row0 = buf + ln15 * 32;                                       \
      bh0.v = *(const u32x4*)(row0 + ((q ^ sw) * 4));                          \
      bl0.v = *(const u32x4*)(row0 + (((4 + q) ^ sw) * 4));                    \
      const u32* row1 = buf + (16 + ln15) * 32;                                \
      bh1.v = *(const u32x4*)(row1 + ((q ^ sw) * 4));                          \
      bl1.v = *(const u32x4*)(row1 + (((4 + q) ^ sw) * 4));                    \
    }                                                                          \
    asm volatile("s_waitcnt lgkmcnt(0)" ::: "memory");                         \
    __builtin_amdgcn_sched_barrier(0);                                         \
    if (DO_STAGE) {                                                            \
      stage4k(wt + (size_t)((t0 + (I) + 2) * 4 + nq) * 1024,                   \
              mybuf + ((SLOT)) * 1024, lane);                                  \
      const float* xp = xt + (size_t)(t0 + (I) + 2) * R_TOTAL + r0;            \
      xn[SLOT][0] = *(const f32x4*)(xp + 0 + q * 4);                           \
      xn[SLOT][1] = *(const f32x4*)(xp + 16 + q * 4);                          \
      xn[SLOT][2] = *(const f32x4*)(xp + 32 + q * 4);                          \
      xn[SLOT][3] = *(const f32x4*)(xp + 48 + q * 4);                          \
    }                                                                          \
    __builtin_amdgcn_sched_barrier(0);                                         \
    __builtin_amdgcn_s_setprio(1);                                             \
    _Pragma("unroll")                                                          \
    for (int f = 0; f < 4; ++f) {                                              \
      f32x4 Y = __builtin_amdgcn_mfma_f32_16x16x32_bf16(Ah[f].s, bh0.s, zero4, 0, 0, 0); \
      Y = __builtin_amdgcn_mfma_f32_16x16x32_bf16(Ah[f].s, bl0.s, Y, 0, 0, 0); \
      Y = __builtin_amdgcn_mfma_f32_16x16x32_bf16(Al[f].s, bh0.s, Y, 0, 0, 0); \
      acc[f][0] += xlc[f] * Y;                                                 \
    }                                                                          \
    _Pragma("unroll")                                                          \
    for (int f = 0; f < 4; ++f) {                                              \
      f32x4 Y = __builtin_amdgcn_mfma_f32_16x16x32_bf16(Ah[f].s, bh1.s, zero4, 0, 0, 0); \
      Y = __builtin_amdgcn_mfma_f32_16x16x32_bf16(Ah[f].s, bl1.s, Y, 0, 0, 0); \
      Y = __builtin_amdgcn_mfma_f32_16x16x32_bf16(Al[f].s, bh1.s, Y, 0, 0, 0); \
      acc[f][1] += xlc[f] * Y;                                                 \
    }                                                                          \
    __builtin_amdgcn_s_setprio(0);                                             \
    __builtin_amdgcn_sched_barrier(0);                                         \
  }

// ---------------- main layer kernel ----------------
// 16 waves: kh = w&3 (K quarter), nq = w>>2 (N quarter). LDS 128 KB dynamic.
// waves_per_eu(4,4): allocator targets exactly 4 waves/EU -> 128-VGPR budget
// (the fix for the R5/R9 VGPR-64 spill artifact).
template <int NT, bool RELU, bool STORE_X>
__global__ __launch_bounds__(1024)
__attribute__((amdgpu_waves_per_eu(4, 4))) void layer_mfma(
    const float* __restrict__ xt,    // NT x R (transposed prev activation)
    const float* __restrict__ x0t,   // 32 x R
    const u32* __restrict__ wt,      // NT*4 quarter images (1024 u32 each)
    const float* __restrict__ bias,  // 128
    float* __restrict__ xoutT,       // 128 x R (if STORE_X)
    float* __restrict__ osum)        // d_out + layer offset, stride 384
{
  constexpr int HT = NT / 4;
  static_assert((HT & 1) == 0 && HT >= 4, "pair-loop needs even HT >= 4");
  extern __shared__ u32 smem[];      // 128 KB: 16 waves x 2048 u32

  const int tid = threadIdx.x;
  const int w = tid >> 6, lane = tid & 63;
  const int ln15 = lane & 15, q = lane >> 4;
  const int kh = w & 3, nq = w >> 2;
  const int r0 = blockIdx.x * 64;
  const int sw = ln15 & 7;
  u32* mybuf = smem + w * 2048;

  // ---- loop-invariant A fragments: split x0 rows (A[i=ln15][k=q*8+j]) ----
  PackU Ah[4], Al[4];
  #pragma unroll
  for (int f = 0; f < 4; ++f) {
    const int rbase = r0 + f * 16 + ln15;
    float e[8];
    #pragma unroll
    for (int j = 0; j < 8; ++j) e[j] = x0t[(size_t)(q * 8 + j) * R_TOTAL + rbase];
    #pragma unroll
    for (int jj = 0; jj < 4; ++jj) {
      float z0 = e[2 * jj], z1 = e[2 * jj + 1];
      Ah[f].u[jj] = pack_trunc(z0, z1);
      float h0 = __uint_as_float(__float_as_uint(z0) & 0xffff0000u);
      float h1 = __uint_as_float(__float_as_uint(z1) & 0xffff0000u);
      Al[f].u[jj] = pack_trunc(z0 - h0, z1 - h1);
    }
  }

  f32x4 acc[4][2];
  #pragma unroll
  for (int f = 0; f < 4; ++f)
    #pragma unroll
    for (int c = 0; c < 2; ++c) acc[f][c] = f32x4{0.f, 0.f, 0.f, 0.f};
  const f32x4 zero4 = {0.f, 0.f, 0.f, 0.f};

  const int t0 = kh * HT;

  // ---- prologue: 2-deep prefetch (groups 0 and 1), issue order stage,xl ----
  f32x4 xn[2][4];
  stage4k(wt + (size_t)(t0 * 4 + nq) * 1024, mybuf, lane);
  {
    const float* xp = xt + (size_t)t0 * R_TOTAL + r0;
    xn[0][0] = *(const f32x4*)(xp + 0 + q * 4);
    xn[0][1] = *(const f32x4*)(xp + 16 + q * 4);
    xn[0][2] = *(const f32x4*)(xp + 32 + q * 4);
    xn[0][3] = *(const f32x4*)(xp + 48 + q * 4);
  }
  stage4k(wt + (size_t)((t0 + 1) * 4 + nq) * 1024, mybuf + 1024, lane);
  {
    const float* xp = xt + (size_t)(t0 + 1) * R_TOTAL + r0;
    xn[1][0] = *(const f32x4*)(xp + 0 + q * 4);
    xn[1][1] = *(const f32x4*)(xp + 16 + q * 4);
    xn[1][2] = *(const f32x4*)(xp + 32 + q * 4);
    xn[1][3] = *(const f32x4*)(xp + 48 + q * 4);
  }
  __builtin_amdgcn_sched_barrier(0);

  // ---- steady state: every in-loop iter stages (i+2), waits vmcnt(8) ----
  for (int i = 0; i < HT - 2; i += 2) {
    KITER(i, 0, 0x0F78, 1);
    KITER(i + 1, 1, 0x0F78, 1);
  }
  // ---- peeled last pair: no staging; final iter drains to vmcnt(0) ----
  KITER(HT - 2, 0, 0x0F78, 0);
  KITER(HT - 1, 1, 0x0F70, 0);

  // ---------------- epilogue: 4-way partial reduction ----------------
  __syncthreads();                  // K-loop LDS regions now reusable
  if (kh != 0) {                    // dump partial acc into own region (8 KB)
    u32* reg = mybuf;
    #pragma unroll
    for (int f = 0; f < 4; ++f)
      #pragma unroll
      for (int c = 0; c < 2; ++c)
        *(f32x4*)(reg + ((size_t)(f * 2 + c) * 64 + lane) * 4) = acc[f][c];
  }
  __syncthreads();
  if (kh == 0) {
    float bs[2];
    #pragma unroll
    for (int c = 0; c < 2; ++c) bs[c] = bias[nq * 32 + c * 16 + ln15];

    f32x4 vv[4][2];
    #pragma unroll
    for (int f = 0; f < 4; ++f) {
      #pragma unroll
      for (int c = 0; c < 2; ++c) {
        f32x4 v = acc[f][c];
        #pragma unroll
        for (int p = 1; p < 4; ++p) {     // partners w+1..w+3 (kh=1..3, same nq)
          const u32* reg = smem + (size_t)(w + p) * 2048;
          v += *(const f32x4*)(reg + ((size_t)(f * 2 + c) * 64 + lane) * 4);
        }
        v.x += bs[c]; v.y += bs[c]; v.z += bs[c]; v.w += bs[c];
        if (RELU) {
          v.x = fmaxf(v.x, 0.f); v.y = fmaxf(v.y, 0.f);
          v.z = fmaxf(v.z, 0.f); v.w = fmaxf(v.w, 0.f);
        }
        vv[f][c] = v;
        float s = v.x + v.y + v.z + v.w;       // 4 rows of batch (r0>>4)+f
        s += __shfl_xor(s, 16, 64);
        s += __shfl_xor(s, 32, 64);
        if (q == 0)
          osum[(size_t)((r0 >> 4) + f) * 384 + nq * 32 + c * 16 + ln15] = s;
      }
    }

    if (STORE_X) {
      // transpose via own LDS region, then 64B-contiguous stores to XT.
      u32* myreg = mybuf;
      #pragma unroll
      for (int f = 0; f < 4; ++f)
        #pragma unroll
        for (int c = 0; c < 2; ++c)
          *(f32x4*)(myreg + ((size_t)(f * 2 + c) * 64 + lane) * 4) = vv[f][c];
      // element (r_local, lcol): frag (f=r>>4, c=lcol>>4), lane q=(r>>2)&3,
      // ln15=lcol&15, comp rr=r&3. Round (c,s): lane -> col=c*16+(lane>>2),
      // r_local = s*16 + (lane&3)*4.
      #pragma unroll
      for (int c = 0; c < 2; ++c) {
        #pragma unroll
        for (int s = 0; s < 4; ++s) {
          f32x4 vr = *(const f32x4*)(myreg +
              ((size_t)(s * 2 + c) * 64 + (lane & 3) * 16 + (lane >> 2)) * 4);
          const int col = nq * 32 + c * 16 + (lane >> 2);
          *(f32x4*)&xoutT[(size_t)col * R_TOTAL + r0 + s * 16 + (lane & 3) * 4] = vr;
        }
      }
    }
  }
}

extern "C" void kernel_launch(void* const* d_in, const int* in_sizes, int n_in,
                              void* d_out, int out_size, void* d_ws, size_t ws_size,
                              hipStream_t stream) {
  const float* in = (const float*)d_in[0];
  const float* W0 = (const float*)d_in[1];
  const float* b0 = (const float*)d_in[2];
  const float* W1 = (const float*)d_in[3];
  const float* b1 = (const float*)d_in[4];
  const float* W2 = (const float*)d_in[5];
  const float* b2 = (const float*)d_in[6];
  float* out = (float*)d_out;

  float* X0T = (float*)d_ws;                         // 32 x 16384   (2 MB)
  float* X1T = X0T + (size_t)32 * R_TOTAL;           // 128 x 16384  (8 MB)
  float* X2T = X1T + (size_t)128 * R_TOTAL;          // 128 x 16384  (8 MB)
  u32* Wt0 = (u32*)(X2T + (size_t)128 * R_TOTAL);    // 32*4*1024 u32  (0.5 MB)
  u32* Wt1 = Wt0 + (size_t)32 * 4 * 1024;            // 128*4*1024 u32 (2 MB)
  u32* Wt2 = Wt1 + (size_t)128 * 4 * 1024;           // 128*4*1024 u32 (2 MB)
  // total ws: 22.5 MB

  prep_all<<<1280, 256, 0, stream>>>(in, X0T, W0, Wt0, W1, Wt1, W2, Wt2);

  constexpr size_t kLds = 16 * 2048 * sizeof(u32);   // 128 KB dynamic LDS

  layer_mfma<32, true, true><<<256, 1024, kLds, stream>>>(X0T, X0T, Wt0, b0, X1T, out + 0);
  layer_mfma<128, true, true><<<256, 1024, kLds, stream>>>(X1T, X0T, Wt1, b1, X2T, out + 128);
  layer_mfma<128, false, false><<<256, 1024, kLds, stream>>>(X2T, X0T, Wt2, b2, nullptr, out + 256);
}

// Round 10
// 184.643 us; speedup vs baseline: 1.9899x; 1.9806x over previous
//
#include <hip/hip_runtime.h>

// CIN_51539607712 — R12: R11 with the staging-slot bug fixed (one token).
// R11 staged tile I+2 into slot (I+1)&1 — clobbering the un-consumed tile
// I+1 (absmax 21.4). Correct destination is slot (I+2)&1 = I&1 = SLOT,
// exactly as R4 had it. No other changes: the occupancy experiment stays
// unconfounded.
// Structure: 4 waves/SIMD via TWO 512-thr blocks/CU (1024-thr route dead:
// R5/R9/R10 all hit a hard VGPR=64 allocation -> 230 MB spill).
// Grid 512 = 256 r-tiles x 2 col-halves. Block = 64 rows x 64 cols, 8 waves:
// kh = w>>1 (K quarter, 0..3), nq = w&1 (col quarter within half).
// Per-wave iteration BIT-IDENTICAL to R4 (best measured: 52.9 us big layers):
// 64r x 32c, 24 MFMA, 4 ds_read_b128, private 4 KB W dbuf, barrier-free
// K-loop, depth-2 counted-vmcnt pipeline (8-op groups, vmcnt(8) steady).
// LDS 64 KB static -> 2 blocks/CU = 16 waves/CU = 4 waves/SIMD.
// out[r,n] = sum_h xl[r,h] * Y_h[r,n],  Y_h[r,n] = sum_m x0[r,m] W[h*32+m,n].
// Y via 3 bf16 MFMAs (x0h*wh + x0h*wl + x0l*wh), then fp32 fma by xl (exact).
// Epilogue: 4-way partial reduction (kh=1..3 dump LDS, kh=0 reduces).

typedef unsigned int u32;
typedef __attribute__((ext_vector_type(8))) short short8;
typedef __attribute__((ext_vector_type(4))) float f32x4;
typedef __attribute__((ext_vector_type(4))) u32 u32x4;

#define R_TOTAL 16384
#define GLOBAL_AS __attribute__((address_space(1)))
#define LDS_AS __attribute__((address_space(3)))

union PackU { u32 u[4]; short8 s; };
union PackB { u32x4 v; short8 s; };

// pack bf16(a) into low half, bf16(b) into high half (truncation)
__device__ __forceinline__ u32 pack_trunc(float a, float b) {
  return __builtin_amdgcn_perm(__float_as_uint(b), __float_as_uint(a), 0x07060302u);
}

// ---------------- fused prep kernel ----------------
// blocks 0..127: build X0T[m][b*16+d] = in[b][m][d]  (32 x 16384)
// blocks 128..255 / 256..767 / 768..1279: swizzle W0 / W1 / W2.
__device__ __forceinline__ void build_x0t_body(const float* __restrict__ in,
                                               float* __restrict__ x0t,
                                               int bid, int tid, float* t) {
  const int b0 = bid * 8;
  #pragma unroll
  for (int rep = 0; rep < 4; ++rep) {
    int idx = tid + rep * 256;
    *(float4*)&t[idx * 4] = *(const float4*)&in[(size_t)b0 * 512 + idx * 4];
  }
  __syncthreads();
  #pragma unroll
  for (int rep = 0; rep < 4; ++rep) {
    int idx = tid + rep * 256;     // 0..1023: m(32) x bl(8) x dq(4)
    int m = idx >> 5, rem = idx & 31;
    int bl = rem >> 2, dq = rem & 3;
    *(float4*)&x0t[(size_t)m * R_TOTAL + (b0 + bl) * 16 + dq * 4] =
        *(const float4*)&t[bl * 512 + m * 16 + dq * 4];
  }
}

// Block (t = bid>>2, nq = bid&3). Image: [nl 0..31][p 0..7] 16B blocks; position
// p holds logical block l = p ^ (nl&7); l = h*4+q -> split-part h of
// W[t*32+q*8+j][nq*32+nl], j pairs packed (even=lo half, odd=hi half).
__device__ __forceinline__ void swizzle_body(const float* __restrict__ W,
                                             u32* __restrict__ wt,
                                             int bid, int tid, float* wl) {
  const int t = bid >> 2, nq = bid & 3;
  {
    int kk = tid >> 3, c4 = tid & 7;
    float4 v = *(const float4*)&W[(size_t)(t * 32 + kk) * 128 + nq * 32 + c4 * 4];
    wl[kk * 33 + c4 * 4 + 0] = v.x;
    wl[kk * 33 + c4 * 4 + 1] = v.y;
    wl[kk * 33 + c4 * 4 + 2] = v.z;
    wl[kk * 33 + c4 * 4 + 3] = v.w;
  }
  __syncthreads();
  {
    int nl = tid >> 3, p = tid & 7;
    int l = p ^ (nl & 7);
    int h = l >> 2, q = l & 3;
    u32 o[4];
    #pragma unroll
    for (int jj = 0; jj < 4; ++jj) {
      float v0 = wl[(q * 8 + 2 * jj + 0) * 33 + nl];
      float v1 = wl[(q * 8 + 2 * jj + 1) * 33 + nl];
      if (h == 1) {
        v0 -= __uint_as_float(__float_as_uint(v0) & 0xffff0000u);
        v1 -= __uint_as_float(__float_as_uint(v1) & 0xffff0000u);
      }
      o[jj] = pack_trunc(v0, v1);
    }
    *(u32x4*)(wt + (size_t)(t * 4 + nq) * 1024 + nl * 32 + p * 4) =
        u32x4{o[0], o[1], o[2], o[3]};
  }
}

__global__ __launch_bounds__(256) void prep_all(
    const float* __restrict__ in, float* __restrict__ x0t,
    const float* __restrict__ W0, u32* __restrict__ wt0,
    const float* __restrict__ W1, u32* __restrict__ wt1,
    const float* __restrict__ W2, u32* __restrict__ wt2) {
  __shared__ float sh[4096];
  const int b = blockIdx.x, tid = threadIdx.x;
  if (b < 128)      build_x0t_body(in, x0t, b, tid, sh);
  else if (b < 256) swizzle_body(W0, wt0, b - 128, tid, sh);
  else if (b < 768) swizzle_body(W1, wt1, b - 256, tid, sh);
  else              swizzle_body(W2, wt2, b - 768, tid, sh);
}

// ---------------- per-wave tile staging: 4096 B via global_load_lds ----------
__device__ __forceinline__ void stage4k(const u32* g, u32* l, int lane) {
  const GLOBAL_AS u32* gp = (const GLOBAL_AS u32*)g;
  LDS_AS u32* lp = (LDS_AS u32*)l;
  #pragma unroll
  for (int i = 0; i < 4; ++i)
    __builtin_amdgcn_global_load_lds(gp + i * 256 + lane * 4, lp + i * 256, 16, 0, 0);
}

// K-loop iteration. WAITIMM: 0x0F78 = vmcnt(8) (group I done, group I+1's 8
// vmem ops in flight), 0x0F70 = vmcnt(0) (peeled last iter). SLOT = I&1.
// Group issue order is always [stage4k(4), xl(4)] -> 8 vmem ops per group.
// Staging destination: tile I+2 -> slot (I+2)&1 = SLOT (the R11 bug was here).
#define KITER(I, SLOT, WAITIMM, DO_STAGE)                                      \
  {                                                                            \
    __builtin_amdgcn_s_waitcnt(WAITIMM);                                       \
    __builtin_amdgcn_sched_barrier(0);                                         \
    f32x4 xlc[4];                                                              \
    xlc[0] = xn[SLOT][0]; xlc[1] = xn[SLOT][1];                                \
    xlc[2] = xn[SLOT][2]; xlc[3] = xn[SLOT][3];                                \
    const u32* buf = mybuf + (SLOT) * 1024;                                    \
    PackB bh0, bl0, bh1, bl1;                                                  \
    {                                                                          \
      const u32* row0 = buf + ln15 * 32;                                       \
      bh0.v = *(const u32x4*)(row0 + ((q ^ sw) * 4));                          \
      bl0.v = *(const u32x4*)(row0 + (((4 + q) ^ sw) * 4));                    \
      const u32* row1 = buf + (16 + ln15) * 32;                                \
      bh1.v = *(const u32x4*)(row1 + ((q ^ sw) * 4));                          \
      bl1.v = *(const u32x4*)(row1 + (((4 + q) ^ sw) * 4));                    \
    }                                                                          \
    asm volatile("s_waitcnt lgkmcnt(0)" ::: "memory");                         \
    __builtin_amdgcn_sched_barrier(0);                                         \
    if (DO_STAGE) {                                                            \
      stage4k(wt + (size_t)((t0 + (I) + 2) * 4 + nqg) * 1024,                  \
              mybuf + (SLOT) * 1024, lane);                                    \
      const float* xp = xt + (size_t)(t0 + (I) + 2) * R_TOTAL + r0;            \
      xn[SLOT][0] = *(const f32x4*)(xp + 0 + q * 4);                           \
      xn[SLOT][1] = *(const f32x4*)(xp + 16 + q * 4);                          \
      xn[SLOT][2] = *(const f32x4*)(xp + 32 + q * 4);                          \
      xn[SLOT][3] = *(const f32x4*)(xp + 48 + q * 4);                          \
    }                                                                          \
    __builtin_amdgcn_sched_barrier(0);                                         \
    __builtin_amdgcn_s_setprio(1);                                             \
    _Pragma("unroll")                                                          \
    for (int f = 0; f < 4; ++f) {                                              \
      f32x4 Y = __builtin_amdgcn_mfma_f32_16x16x32_bf16(Ah[f].s, bh0.s, zero4, 0, 0, 0); \
      Y = __builtin_amdgcn_mfma_f32_16x16x32_bf16(Ah[f].s, bl0.s, Y, 0, 0, 0); \
      Y = __builtin_amdgcn_mfma_f32_16x16x32_bf16(Al[f].s, bh0.s, Y, 0, 0, 0); \
      acc[f][0] += xlc[f] * Y;                                                 \
    }                                                                          \
    _Pragma("unroll")                                                          \
    for (int f = 0; f < 4; ++f) {                                              \
      f32x4 Y = __builtin_amdgcn_mfma_f32_16x16x32_bf16(Ah[f].s, bh1.s, zero4, 0, 0, 0); \
      Y = __builtin_amdgcn_mfma_f32_16x16x32_bf16(Ah[f].s, bl1.s, Y, 0, 0, 0); \
      Y = __builtin_amdgcn_mfma_f32_16x16x32_bf16(Al[f].s, bh1.s, Y, 0, 0, 0); \
      acc[f][1] += xlc[f] * Y;                                                 \
    }                                                                          \
    __builtin_amdgcn_s_setprio(0);                                             \
    __builtin_amdgcn_sched_barrier(0);                                         \
  }

// ---------------- main layer kernel ----------------
// Block 64 rows x 64 cols, 8 waves: kh = w>>1 (K quarter), nq = w&1.
// Global col quarter nqg = (bid&1)*2 + nq. Grid 512, 64 KB static LDS ->
// 2 blocks/CU = 16 waves/CU = 4 waves/SIMD.
template <int NT, bool RELU, bool STORE_X>
__global__ __launch_bounds__(512, 2) void layer_mfma(
    const float* __restrict__ xt,    // NT x R (transposed prev activation)
    const float* __restrict__ x0t,   // 32 x R
    const u32* __restrict__ wt,      // NT*4 quarter images (1024 u32 each)
    const float* __restrict__ bias,  // 128
    float* __restrict__ xoutT,       // 128 x R (if STORE_X)
    float* __restrict__ osum)        // d_out + layer offset, stride 384
{
  constexpr int HT = NT / 4;
  static_assert((HT & 1) == 0 && HT >= 4, "pair-loop needs even HT >= 4");
  __shared__ u32 smem[16384];        // 64 KB: 8 waves x 2048 u32 (4 KB dbuf x2)

  const int tid = threadIdx.x;
  const int w = tid >> 6, lane = tid & 63;
  const int ln15 = lane & 15, q = lane >> 4;
  const int kh = w >> 1, nq = w & 1;
  const int r0 = (blockIdx.x >> 1) * 64;
  const int nqg = (blockIdx.x & 1) * 2 + nq;   // global col quarter 0..3
  const int sw = ln15 & 7;
  u32* mybuf = smem + w * 2048;

  // ---- loop-invariant A fragments: split x0 rows (A[i=ln15][k=q*8+j]) ----
  PackU Ah[4], Al[4];
  #pragma unroll
  for (int f = 0; f < 4; ++f) {
    const int rbase = r0 + f * 16 + ln15;
    float e[8];
    #pragma unroll
    for (int j = 0; j < 8; ++j) e[j] = x0t[(size_t)(q * 8 + j) * R_TOTAL + rbase];
    #pragma unroll
    for (int jj = 0; jj < 4; ++jj) {
      float z0 = e[2 * jj], z1 = e[2 * jj + 1];
      Ah[f].u[jj] = pack_trunc(z0, z1);
      float h0 = __uint_as_float(__float_as_uint(z0) & 0xffff0000u);
      float h1 = __uint_as_float(__float_as_uint(z1) & 0xffff0000u);
      Al[f].u[jj] = pack_trunc(z0 - h0, z1 - h1);
    }
  }

  f32x4 acc[4][2];
  #pragma unroll
  for (int f = 0; f < 4; ++f)
    #pragma unroll
    for (int c = 0; c < 2; ++c) acc[f][c] = f32x4{0.f, 0.f, 0.f, 0.f};
  const f32x4 zero4 = {0.f, 0.f, 0.f, 0.f};

  const int t0 = kh * HT;

  // ---- prologue: 2-deep prefetch (groups 0 and 1), issue order stage,xl ----
  f32x4 xn[2][4];
  stage4k(wt + (size_t)(t0 * 4 + nqg) * 1024, mybuf, lane);
  {
    const float* xp = xt + (size_t)t0 * R_TOTAL + r0;
    xn[0][0] = *(const f32x4*)(xp + 0 + q * 4);
    xn[0][1] = *(const f32x4*)(xp + 16 + q * 4);
    xn[0][2] = *(const f32x4*)(xp + 32 + q * 4);
    xn[0][3] = *(const f32x4*)(xp + 48 + q * 4);
  }
  stage4k(wt + (size_t)((t0 + 1) * 4 + nqg) * 1024, mybuf + 1024, lane);
  {
    const float* xp = xt + (size_t)(t0 + 1) * R_TOTAL + r0;
    xn[1][0] = *(const f32x4*)(xp + 0 + q * 4);
    xn[1][1] = *(const f32x4*)(xp + 16 + q * 4);
    xn[1][2] = *(const f32x4*)(xp + 32 + q * 4);
    xn[1][3] = *(const f32x4*)(xp + 48 + q * 4);
  }
  __builtin_amdgcn_sched_barrier(0);

  // ---- steady state: every in-loop iter stages (i+2), waits vmcnt(8) ----
  for (int i = 0; i < HT - 2; i += 2) {
    KITER(i, 0, 0x0F78, 1);
    KITER(i + 1, 1, 0x0F78, 1);
  }
  // ---- peeled last pair: no staging; final iter drains to vmcnt(0) ----
  KITER(HT - 2, 0, 0x0F78, 0);
  KITER(HT - 1, 1, 0x0F70, 0);

  // ---------------- epilogue: 4-way partial reduction ----------------
  __syncthreads();                  // K-loop LDS regions now reusable
  if (kh != 0) {                    // dump partial acc into own region (8 KB)
    u32* reg = mybuf;
    #pragma unroll
    for (int f = 0; f < 4; ++f)
      #pragma unroll
      for (int c = 0; c < 2; ++c)
        *(f32x4*)(reg + ((size_t)(f * 2 + c) * 64 + lane) * 4) = acc[f][c];
  }
  __syncthreads();
  if (kh == 0) {
    float bs[2];
    #pragma unroll
    for (int c = 0; c < 2; ++c) bs[c] = bias[nqg * 32 + c * 16 + ln15];

    f32x4 vv[4][2];
    #pragma unroll
    for (int f = 0; f < 4; ++f) {
      #pragma unroll
      for (int c = 0; c < 2; ++c) {
        f32x4 v = acc[f][c];
        #pragma unroll
        for (int p = 1; p < 4; ++p) {     // partners w+2p (kh=1..3, same nq)
          const u32* reg = smem + (size_t)(w + 2 * p) * 2048;
          v += *(const f32x4*)(reg + ((size_t)(f * 2 + c) * 64 + lane) * 4);
        }
        v.x += bs[c]; v.y += bs[c]; v.z += bs[c]; v.w += bs[c];
        if (RELU) {
          v.x = fmaxf(v.x, 0.f); v.y = fmaxf(v.y, 0.f);
          v.z = fmaxf(v.z, 0.f); v.w = fmaxf(v.w, 0.f);
        }
        vv[f][c] = v;
        float s = v.x + v.y + v.z + v.w;       // 4 rows of batch (r0>>4)+f
        s += __shfl_xor(s, 16, 64);
        s += __shfl_xor(s, 32, 64);
        if (q == 0)
          osum[(size_t)((r0 >> 4) + f) * 384 + nqg * 32 + c * 16 + ln15] = s;
      }
    }

    if (STORE_X) {
      // transpose via own LDS region (regions 0..1, free), 64B stores to XT.
      u32* myreg = mybuf;
      #pragma unroll
      for (int f = 0; f < 4; ++f)
        #pragma unroll
        for (int c = 0; c < 2; ++c)
          *(f32x4*)(myreg + ((size_t)(f * 2 + c) * 64 + lane) * 4) = vv[f][c];
      // element (r_local, lcol): frag (f=r>>4, c=lcol>>4), lane q=(r>>2)&3,
      // ln15=lcol&15, comp rr=r&3. Round (c,s): lane -> col=c*16+(lane>>2),
      // r_local = s*16 + (lane&3)*4.
      #pragma unroll
      for (int c = 0; c < 2; ++c) {
        #pragma unroll
        for (int s = 0; s < 4; ++s) {
          f32x4 vr = *(const f32x4*)(myreg +
              ((size_t)(s * 2 + c) * 64 + (lane & 3) * 16 + (lane >> 2)) * 4);
          const int col = nqg * 32 + c * 16 + (lane >> 2);
          *(f32x4*)&xoutT[(size_t)col * R_TOTAL + r0 + s * 16 + (lane & 3) * 4] = vr;
        }
      }
    }
  }
}

extern "C" void kernel_launch(void* const* d_in, const int* in_sizes, int n_in,
                              void* d_out, int out_size, void* d_ws, size_t ws_size,
                              hipStream_t stream) {
  const float* in = (const float*)d_in[0];
  const float* W0 = (const float*)d_in[1];
  const float* b0 = (const float*)d_in[2];
  const float* W1 = (const float*)d_in[3];
  const float* b1 = (const float*)d_in[4];
  const float* W2 = (const float*)d_in[5];
  const float* b2 = (const float*)d_in[6];
  float* out = (float*)d_out;

  float* X0T = (float*)d_ws;                         // 32 x 16384   (2 MB)
  float* X1T = X0T + (size_t)32 * R_TOTAL;           // 128 x 16384  (8 MB)
  float* X2T = X1T + (size_t)128 * R_TOTAL;          // 128 x 16384  (8 MB)
  u32* Wt0 = (u32*)(X2T + (size_t)128 * R_TOTAL);    // 32*4*1024 u32  (0.5 MB)
  u32* Wt1 = Wt0 + (size_t)32 * 4 * 1024;            // 128*4*1024 u32 (2 MB)
  u32* Wt2 = Wt1 + (size_t)128 * 4 * 1024;           // 128*4*1024 u32 (2 MB)
  // total ws: 22.5 MB

  prep_all<<<1280, 256, 0, stream>>>(in, X0T, W0, Wt0, W1, Wt1, W2, Wt2);

  layer_mfma<32, true, true><<<512, 512, 0, stream>>>(X0T, X0T, Wt0, b0, X1T, out + 0);
  layer_mfma<128, true, true><<<512, 512, 0, stream>>>(X1T, X0T, Wt1, b1, X2T, out + 128);
  layer_mfma<128, false, false><<<512, 512, 0, stream>>>(X2T, X0T, Wt2, b2, nullptr, out + 256);
}

// Round 11
// 163.043 us; speedup vs baseline: 2.2535x; 1.1325x over previous
//
#include <hip/hip_runtime.h>

// CIN_51539607712 — R13: 2-MFMA split. After six null scheduling levers
// (R4 latency, R6/R12 occupancy, R7 LDS latency, R8 TA/shared-W), the
// invariant is ~21 us matrix-busy per big layer in a ~53 us envelope.
// So shrink the matrix work: drop the x0-low correction term (x0l*Wh) and
// convert x0->bf16 with ROUND-TO-NEAREST (v_cvt_pk_bf16_f32) instead of
// truncation — dropped residual x0l is unbiased and <= 2^-9 relative.
// W stays EXACT (Wh + Wl both kept), so prep, images, ds_reads and the
// vmcnt ledger are all unchanged. MFMA/iter: 24 -> 16 (-33% matrix work).
// Error budget: ~sqrt(32)*2^-9*|x0|*|W| per Y, ~sqrt(128)x per out ~ 0.01-
// 0.03 stat; threshold 0.4525, current absmax 0.0625 -> ample headroom.
// Geometry = R4 champion: grid 256, 512 thr, 8 waves (kh = w&1, nq = w>>1),
// 64-row blocks, per-wave private 4 KB W dbuf, barrier-free counted-vmcnt
// K-loop. Prep fused into one launch (R7+).
// out[r,n] = sum_h xl[r,h] * Y_h[r,n],  Y_h[r,n] = sum_m x0[r,m] W[h*32+m,n].
// Y via 2 bf16 MFMAs (x0h*wh + x0h*wl), then fp32 fma by xl.

typedef unsigned int u32;
typedef __attribute__((ext_vector_type(8))) short short8;
typedef __attribute__((ext_vector_type(4))) float f32x4;
typedef __attribute__((ext_vector_type(4))) u32 u32x4;

#define R_TOTAL 16384
#define GLOBAL_AS __attribute__((address_space(1)))
#define LDS_AS __attribute__((address_space(3)))

union PackU { u32 u[4]; short8 s; };
union PackB { u32x4 v; short8 s; };

// pack bf16(a) into low half, bf16(b) into high half (truncation) — W prep
__device__ __forceinline__ u32 pack_trunc(float a, float b) {
  return __builtin_amdgcn_perm(__float_as_uint(b), __float_as_uint(a), 0x07060302u);
}

// pack with round-to-nearest-even — A fragments (halves the dropped residual)
__device__ __forceinline__ u32 pack_rne(float a, float b) {
  u32 r;
  asm("v_cvt_pk_bf16_f32 %0, %1, %2" : "=v"(r) : "v"(a), "v"(b));
  return r;
}

// ---------------- fused prep kernel ----------------
// blocks 0..127: build X0T[m][b*16+d] = in[b][m][d]  (32 x 16384)
// blocks 128..255 / 256..767 / 768..1279: swizzle W0 / W1 / W2.
__device__ __forceinline__ void build_x0t_body(const float* __restrict__ in,
                                               float* __restrict__ x0t,
                                               int bid, int tid, float* t) {
  const int b0 = bid * 8;
  #pragma unroll
  for (int rep = 0; rep < 4; ++rep) {
    int idx = tid + rep * 256;
    *(float4*)&t[idx * 4] = *(const float4*)&in[(size_t)b0 * 512 + idx * 4];
  }
  __syncthreads();
  #pragma unroll
  for (int rep = 0; rep < 4; ++rep) {
    int idx = tid + rep * 256;     // 0..1023: m(32) x bl(8) x dq(4)
    int m = idx >> 5, rem = idx & 31;
    int bl = rem >> 2, dq = rem & 3;
    *(float4*)&x0t[(size_t)m * R_TOTAL + (b0 + bl) * 16 + dq * 4] =
        *(const float4*)&t[bl * 512 + m * 16 + dq * 4];
  }
}

// Block (t = bid>>2, nq = bid&3). Image: [nl 0..31][p 0..7] 16B blocks; position
// p holds logical block l = p ^ (nl&7); l = h*4+q -> split-part h of
// W[t*32+q*8+j][nq*32+nl], j pairs packed (even=lo half, odd=hi half).
__device__ __forceinline__ void swizzle_body(const float* __restrict__ W,
                                             u32* __restrict__ wt,
                                             int bid, int tid, float* wl) {
  const int t = bid >> 2, nq = bid & 3;
  {
    int kk = tid >> 3, c4 = tid & 7;
    float4 v = *(const float4*)&W[(size_t)(t * 32 + kk) * 128 + nq * 32 + c4 * 4];
    wl[kk * 33 + c4 * 4 + 0] = v.x;
    wl[kk * 33 + c4 * 4 + 1] = v.y;
    wl[kk * 33 + c4 * 4 + 2] = v.z;
    wl[kk * 33 + c4 * 4 + 3] = v.w;
  }
  __syncthreads();
  {
    int nl = tid >> 3, p = tid & 7;
    int l = p ^ (nl & 7);
    int h = l >> 2, q = l & 3;
    u32 o[4];
    #pragma unroll
    for (int jj = 0; jj < 4; ++jj) {
      float v0 = wl[(q * 8 + 2 * jj + 0) * 33 + nl];
      float v1 = wl[(q * 8 + 2 * jj + 1) * 33 + nl];
      if (h == 1) {
        v0 -= __uint_as_float(__float_as_uint(v0) & 0xffff0000u);
        v1 -= __uint_as_float(__float_as_uint(v1) & 0xffff0000u);
      }
      o[jj] = pack_trunc(v0, v1);
    }
    *(u32x4*)(wt + (size_t)(t * 4 + nq) * 1024 + nl * 32 + p * 4) =
        u32x4{o[0], o[1], o[2], o[3]};
  }
}

__global__ __launch_bounds__(256) void prep_all(
    const float* __restrict__ in, float* __restrict__ x0t,
    const float* __restrict__ W0, u32* __restrict__ wt0,
    const float* __restrict__ W1, u32* __restrict__ wt1,
    const float* __restrict__ W2, u32* __restrict__ wt2) {
  __shared__ float sh[4096];
  const int b = blockIdx.x, tid = threadIdx.x;
  if (b < 128)      build_x0t_body(in, x0t, b, tid, sh);
  else if (b < 256) swizzle_body(W0, wt0, b - 128, tid, sh);
  else if (b < 768) swizzle_body(W1, wt1, b - 256, tid, sh);
  else              swizzle_body(W2, wt2, b - 768, tid, sh);
}

// ---------------- per-wave tile staging: 4096 B via global_load_lds ----------
__device__ __forceinline__ void stage4k(const u32* g, u32* l, int lane) {
  const GLOBAL_AS u32* gp = (const GLOBAL_AS u32*)g;
  LDS_AS u32* lp = (LDS_AS u32*)l;
  #pragma unroll
  for (int i = 0; i < 4; ++i)
    __builtin_amdgcn_global_load_lds(gp + i * 256 + lane * 4, lp + i * 256, 16, 0, 0);
}

// K-loop iteration. WAITIMM: 0x0F78 = vmcnt(8) (group I done, group I+1's 8
// vmem ops in flight), 0x0F70 = vmcnt(0) (peeled last iter). SLOT = I&1.
// Group issue order is always [stage4k(4), xl(4)] -> 8 vmem ops per group.
#define KITER(I, SLOT, WAITIMM, DO_STAGE)                                      \
  {                                                                            \
    __builtin_amdgcn_s_waitcnt(WAITIMM);                                       \
    __builtin_amdgcn_sched_barrier(0);                                         \
    f32x4 xlc[4];                                                              \
    xlc[0] = xn[SLOT][0]; xlc[1] = xn[SLOT][1];                                \
    xlc[2] = xn[SLOT][2]; xlc[3] = xn[SLOT][3];                                \
    const u32* buf = mybuf + (SLOT) * 1024;                                    \
    PackB bh0, bl0, bh1, bl1;                                                  \
    {                                                                          \
      const u32* row0 = buf + ln15 * 32;                                       \
      bh0.v = *(const u32x4*)(row0 + ((q ^ sw) * 4));                          \
      bl0.v = *(const u32x4*)(row0 + (((4 + q) ^ sw) * 4));                    \
      const u32* row1 = buf + (16 + ln15) * 32;                                \
      bh1.v = *(const u32x4*)(row1 + ((q ^ sw) * 4));                          \
      bl1.v = *(const u32x4*)(row1 + (((4 + q) ^ sw) * 4));                    \
    }                                                                          \
    asm volatile("s_waitcnt lgkmcnt(0)" ::: "memory");                         \
    __builtin_amdgcn_sched_barrier(0);                                         \
    if (DO_STAGE) {                                                            \
      stage4k(wt + (size_t)((t0 + (I) + 2) * 4 + nq) * 1024,                   \
              mybuf + (SLOT) * 1024, lane);                                    \
      const float* xp = xt + (size_t)(t0 + (I) + 2) * R_TOTAL + r0;            \
      xn[SLOT][0] = *(const f32x4*)(xp + 0 + q * 4);                           \
      xn[SLOT][1] = *(const f32x4*)(xp + 16 + q * 4);                          \
      xn[SLOT][2] = *(const f32x4*)(xp + 32 + q * 4);                          \
      xn[SLOT][3] = *(const f32x4*)(xp + 48 + q * 4);                          \
    }                                                                          \
    __builtin_amdgcn_sched_barrier(0);                                         \
    __builtin_amdgcn_s_setprio(1);                                             \
    _Pragma("unroll")                                                          \
    for (int f = 0; f < 4; ++f) {                                              \
      f32x4 Y = __builtin_amdgcn_mfma_f32_16x16x32_bf16(Ah[f].s, bh0.s, zero4, 0, 0, 0); \
      Y = __builtin_amdgcn_mfma_f32_16x16x32_bf16(Ah[f].s, bl0.s, Y, 0, 0, 0); \
      acc[f][0] += xlc[f] * Y;                                                 \
    }                                                                          \
    _Pragma("unroll")                                                          \
    for (int f = 0; f < 4; ++f) {                                              \
      f32x4 Y = __builtin_amdgcn_mfma_f32_16x16x32_bf16(Ah[f].s, bh1.s, zero4, 0, 0, 0); \
      Y = __builtin_amdgcn_mfma_f32_16x16x32_bf16(Ah[f].s, bl1.s, Y, 0, 0, 0); \
      acc[f][1] += xlc[f] * Y;                                                 \
    }                                                                          \
    __builtin_amdgcn_s_setprio(0);                                             \
    __builtin_amdgcn_sched_barrier(0);                                         \
  }

// ---------------- main layer kernel ----------------
template <int NT, bool RELU, bool STORE_X>
__global__ __launch_bounds__(512, 2) void layer_mfma(
    const float* __restrict__ xt,    // NT x R (transposed prev activation)
    const float* __restrict__ x0t,   // 32 x R
    const u32* __restrict__ wt,      // NT*4 quarter images (1024 u32 each)
    const float* __restrict__ bias,  // 128
    float* __restrict__ xoutT,       // 128 x R (if STORE_X)
    float* __restrict__ osum)        // d_out + layer offset, stride 384
{
  constexpr int HT = NT / 2;
  static_assert((HT & 1) == 0 && HT >= 4, "pair-loop needs even HT >= 4");
  __shared__ u32 smem[16384];        // 64 KB: 8 waves x 2 KB-u32 (4 KB dbuf x2)

  const int tid = threadIdx.x;
  const int w = tid >> 6, lane = tid & 63;
  const int ln15 = lane & 15, q = lane >> 4;
  const int kh = w & 1, nq = w >> 1;
  const int r0 = blockIdx.x * 64;
  const int sw = ln15 & 7;
  u32* mybuf = smem + w * 2048;

  // ---- loop-invariant A fragments: RNE-rounded x0 rows (A[i=ln15][k=q*8+j])
  PackU Ah[4];
  #pragma unroll
  for (int f = 0; f < 4; ++f) {
    const int rbase = r0 + f * 16 + ln15;
    float e[8];
    #pragma unroll
    for (int j = 0; j < 8; ++j) e[j] = x0t[(size_t)(q * 8 + j) * R_TOTAL + rbase];
    #pragma unroll
    for (int jj = 0; jj < 4; ++jj)
      Ah[f].u[jj] = pack_rne(e[2 * jj], e[2 * jj + 1]);
  }

  f32x4 acc[4][2];
  #pragma unroll
  for (int f = 0; f < 4; ++f)
    #pragma unroll
    for (int c = 0; c < 2; ++c) acc[f][c] = f32x4{0.f, 0.f, 0.f, 0.f};
  const f32x4 zero4 = {0.f, 0.f, 0.f, 0.f};

  const int t0 = kh * HT;

  // ---- prologue: 2-deep prefetch (groups 0 and 1), issue order stage,xl ----
  f32x4 xn[2][4];
  stage4k(wt + (size_t)(t0 * 4 + nq) * 1024, mybuf, lane);
  {
    const float* xp = xt + (size_t)t0 * R_TOTAL + r0;
    xn[0][0] = *(const f32x4*)(xp + 0 + q * 4);
    xn[0][1] = *(const f32x4*)(xp + 16 + q * 4);
    xn[0][2] = *(const f32x4*)(xp + 32 + q * 4);
    xn[0][3] = *(const f32x4*)(xp + 48 + q * 4);
  }
  stage4k(wt + (size_t)((t0 + 1) * 4 + nq) * 1024, mybuf + 1024, lane);
  {
    const float* xp = xt + (size_t)(t0 + 1) * R_TOTAL + r0;
    xn[1][0] = *(const f32x4*)(xp + 0 + q * 4);
    xn[1][1] = *(const f32x4*)(xp + 16 + q * 4);
    xn[1][2] = *(const f32x4*)(xp + 32 + q * 4);
    xn[1][3] = *(const f32x4*)(xp + 48 + q * 4);
  }
  __builtin_amdgcn_sched_barrier(0);

  // ---- steady state: every in-loop iter stages (i+2), waits vmcnt(8) ----
  for (int i = 0; i < HT - 2; i += 2) {
    KITER(i, 0, 0x0F78, 1);
    KITER(i + 1, 1, 0x0F78, 1);
  }
  // ---- peeled last pair: no staging; final iter drains to vmcnt(0) ----
  KITER(HT - 2, 0, 0x0F78, 0);
  KITER(HT - 1, 1, 0x0F70, 0);

  // ---------------- epilogue ----------------
  __syncthreads();                  // K-loop LDS regions now reusable
  if (kh == 1) {                    // dump partial acc into own region (8 KB)
    u32* reg = mybuf;
    #pragma unroll
    for (int f = 0; f < 4; ++f)
      #pragma unroll
      for (int c = 0; c < 2; ++c)
        *(f32x4*)(reg + ((size_t)(f * 2 + c) * 64 + lane) * 4) = acc[f][c];
  }
  __syncthreads();
  if (kh == 0) {
    const u32* reg = smem + (w + 1) * 2048;   // partner (kh=1, same nq)
    float bs[2];
    #pragma unroll
    for (int c = 0; c < 2; ++c) bs[c] = bias[nq * 32 + c * 16 + ln15];

    f32x4 vv[4][2];
    #pragma unroll
    for (int f = 0; f < 4; ++f) {
      #pragma unroll
      for (int c = 0; c < 2; ++c) {
        f32x4 part = *(const f32x4*)(reg + ((size_t)(f * 2 + c) * 64 + lane) * 4);
        f32x4 v = acc[f][c] + part;
        v.x += bs[c]; v.y += bs[c]; v.z += bs[c]; v.w += bs[c];
        if (RELU) {
          v.x = fmaxf(v.x, 0.f); v.y = fmaxf(v.y, 0.f);
          v.z = fmaxf(v.z, 0.f); v.w = fmaxf(v.w, 0.f);
        }
        vv[f][c] = v;
        float s = v.x + v.y + v.z + v.w;       // 4 rows of batch (r0>>4)+f
        s += __shfl_xor(s, 16, 64);
        s += __shfl_xor(s, 32, 64);
        if (q == 0)
          osum[(size_t)((r0 >> 4) + f) * 384 + nq * 32 + c * 16 + ln15] = s;
      }
    }

    if (STORE_X) {
      // transpose via own LDS region, then 64B-contiguous stores to XT.
      u32* myreg = mybuf;
      #pragma unroll
      for (int f = 0; f < 4; ++f)
        #pragma unroll
        for (int c = 0; c < 2; ++c)
          *(f32x4*)(myreg + ((size_t)(f * 2 + c) * 64 + lane) * 4) = vv[f][c];
      // element (r_local, lcol): frag (f=r>>4, c=lcol>>4), lane q=(r>>2)&3,
      // ln15=lcol&15, comp rr=r&3. Round (c,s): lane -> col=c*16+(lane>>2),
      // r_local = s*16 + (lane&3)*4.
      #pragma unroll
      for (int c = 0; c < 2; ++c) {
        #pragma unroll
        for (int s = 0; s < 4; ++s) {
          f32x4 vr = *(const f32x4*)(myreg +
              ((size_t)(s * 2 + c) * 64 + (lane & 3) * 16 + (lane >> 2)) * 4);
          const int col = nq * 32 + c * 16 + (lane >> 2);
          *(f32x4*)&xoutT[(size_t)col * R_TOTAL + r0 + s * 16 + (lane & 3) * 4] = vr;
        }
      }
    }
  }
}

extern "C" void kernel_launch(void* const* d_in, const int* in_sizes, int n_in,
                              void* d_out, int out_size, void* d_ws, size_t ws_size,
                              hipStream_t stream) {
  const float* in = (const float*)d_in[0];
  const float* W0 = (const float*)d_in[1];
  const float* b0 = (const float*)d_in[2];
  const float* W1 = (const float*)d_in[3];
  const float* b1 = (const float*)d_in[4];
  const float* W2 = (const float*)d_in[5];
  const float* b2 = (const float*)d_in[6];
  float* out = (float*)d_out;

  float* X0T = (float*)d_ws;                         // 32 x 16384   (2 MB)
  float* X1T = X0T + (size_t)32 * R_TOTAL;           // 128 x 16384  (8 MB)
  float* X2T = X1T + (size_t)128 * R_TOTAL;          // 128 x 16384  (8 MB)
  u32* Wt0 = (u32*)(X2T + (size_t)128 * R_TOTAL);    // 32*4*1024 u32  (0.5 MB)
  u32* Wt1 = Wt0 + (size_t)32 * 4 * 1024;            // 128*4*1024 u32 (2 MB)
  u32* Wt2 = Wt1 + (size_t)128 * 4 * 1024;           // 128*4*1024 u32 (2 MB)
  // total ws: 22.5 MB

  prep_all<<<1280, 256, 0, stream>>>(in, X0T, W0, Wt0, W1, Wt1, W2, Wt2);

  layer_mfma<32, true, true><<<256, 512, 0, stream>>>(X0T, X0T, Wt0, b0, X1T, out + 0);
  layer_mfma<128, true, true><<<256, 512, 0, stream>>>(X1T, X0T, Wt1, b1, X2T, out + 128);
  layer_mfma<128, false, false><<<256, 512, 0, stream>>>(X2T, X0T, Wt2, b2, nullptr, out + 256);
}

// Round 12
// 137.728 us; speedup vs baseline: 2.6677x; 1.1838x over previous
//
#include <hip/hip_runtime.h>

// CIN_51539607712 — R14: 1-MFMA split. Serial-MFMA model (calibrated R4/R13:
// period = ~1040 cy const + 2 waves x N_mfma x 19.4 cy) says N_mfma is the
// only responsive lever. Drop the W-low term: W packed with RNE
// (v_cvt_pk_bf16_f32) in prep, Y = mfma(rne(x0), rne(W)) — 8 MFMA/iter
// (R4: 24, R13: 16). Error: x0l drop doubled absmax 0.0625->0.125; Wl drop
// under RNE adds an independent same-magnitude term -> expect 0.18-0.30 vs
// threshold 0.4525.
// W images halve to 2 KB: 2 global_load_lds + 2 ds_read_b128 per iter,
// vmem group = [stage(2), xl(4)] = 6 -> steady vmcnt(6). LDS wave regions
// unchanged (2048 u32; K-loop slots = 512 u32 each) so epilogue identical.
// Geometry = R4 champion: grid 256, 512 thr, 8 waves (kh = w&1, nq = w>>1),
// 64-row blocks, barrier-free counted-vmcnt K-loop, fused prep.
// out[r,n] = sum_h xl[r,h] * Y_h[r,n],  Y_h[r,n] = sum_m x0[r,m] W[h*32+m,n].

typedef unsigned int u32;
typedef __attribute__((ext_vector_type(8))) short short8;
typedef __attribute__((ext_vector_type(4))) float f32x4;
typedef __attribute__((ext_vector_type(4))) u32 u32x4;

#define R_TOTAL 16384
#define GLOBAL_AS __attribute__((address_space(1)))
#define LDS_AS __attribute__((address_space(3)))

union PackU { u32 u[4]; short8 s; };
union PackB { u32x4 v; short8 s; };

// pack with round-to-nearest-even (both x0 fragments and W prep)
__device__ __forceinline__ u32 pack_rne(float a, float b) {
  u32 r;
  asm("v_cvt_pk_bf16_f32 %0, %1, %2" : "=v"(r) : "v"(a), "v"(b));
  return r;
}

// ---------------- fused prep kernel ----------------
// blocks 0..127: build X0T[m][b*16+d] = in[b][m][d]  (32 x 16384)
// blocks 128..255 / 256..767 / 768..1279: swizzle W0 / W1 / W2.
__device__ __forceinline__ void build_x0t_body(const float* __restrict__ in,
                                               float* __restrict__ x0t,
                                               int bid, int tid, float* t) {
  const int b0 = bid * 8;
  #pragma unroll
  for (int rep = 0; rep < 4; ++rep) {
    int idx = tid + rep * 256;
    *(float4*)&t[idx * 4] = *(const float4*)&in[(size_t)b0 * 512 + idx * 4];
  }
  __syncthreads();
  #pragma unroll
  for (int rep = 0; rep < 4; ++rep) {
    int idx = tid + rep * 256;     // 0..1023: m(32) x bl(8) x dq(4)
    int m = idx >> 5, rem = idx & 31;
    int bl = rem >> 2, dq = rem & 3;
    *(float4*)&x0t[(size_t)m * R_TOTAL + (b0 + bl) * 16 + dq * 4] =
        *(const float4*)&t[bl * 512 + m * 16 + dq * 4];
  }
}

// Block (t = bid>>2, nq = bid&3). 2 KB image: [nl 0..31][p 0..3] 16B blocks;
// position p holds logical block q = p ^ (nl&3); block q = RNE-packed
// W[t*32+q*8+j][nq*32+nl], j pairs packed (even=lo half, odd=hi half).
__device__ __forceinline__ void swizzle_body(const float* __restrict__ W,
                                             u32* __restrict__ wt,
                                             int bid, int tid, float* wl) {
  const int t = bid >> 2, nq = bid & 3;
  {
    int kk = tid >> 3, c4 = tid & 7;
    float4 v = *(const float4*)&W[(size_t)(t * 32 + kk) * 128 + nq * 32 + c4 * 4];
    wl[kk * 33 + c4 * 4 + 0] = v.x;
    wl[kk * 33 + c4 * 4 + 1] = v.y;
    wl[kk * 33 + c4 * 4 + 2] = v.z;
    wl[kk * 33 + c4 * 4 + 3] = v.w;
  }
  __syncthreads();
  if (tid < 128) {
    int nl = tid >> 2, p = tid & 3;
    int q = p ^ (nl & 3);
    u32 o[4];
    #pragma unroll
    for (int jj = 0; jj < 4; ++jj)
      o[jj] = pack_rne(wl[(q * 8 + 2 * jj + 0) * 33 + nl],
                       wl[(q * 8 + 2 * jj + 1) * 33 + nl]);
    *(u32x4*)(wt + (size_t)(t * 4 + nq) * 512 + nl * 16 + p * 4) =
        u32x4{o[0], o[1], o[2], o[3]};
  }
}

__global__ __launch_bounds__(256) void prep_all(
    const float* __restrict__ in, float* __restrict__ x0t,
    const float* __restrict__ W0, u32* __restrict__ wt0,
    const float* __restrict__ W1, u32* __restrict__ wt1,
    const float* __restrict__ W2, u32* __restrict__ wt2) {
  __shared__ float sh[4096];
  const int b = blockIdx.x, tid = threadIdx.x;
  if (b < 128)      build_x0t_body(in, x0t, b, tid, sh);
  else if (b < 256) swizzle_body(W0, wt0, b - 128, tid, sh);
  else if (b < 768) swizzle_body(W1, wt1, b - 256, tid, sh);
  else              swizzle_body(W2, wt2, b - 768, tid, sh);
}

// ---------------- per-wave tile staging: 2048 B via global_load_lds ----------
__device__ __forceinline__ void stage2k(const u32* g, u32* l, int lane) {
  const GLOBAL_AS u32* gp = (const GLOBAL_AS u32*)g;
  LDS_AS u32* lp = (LDS_AS u32*)l;
  #pragma unroll
  for (int i = 0; i < 2; ++i)
    __builtin_amdgcn_global_load_lds(gp + i * 256 + lane * 4, lp + i * 256, 16, 0, 0);
}

// K-loop iteration. WAITIMM: 0x0F76 = vmcnt(6) (group I done, group I+1's 6
// vmem ops in flight), 0x0F70 = vmcnt(0) (peeled last iter). SLOT = I&1.
// Group issue order is always [stage2k(2), xl(4)] -> 6 vmem ops per group.
// Staging destination: tile I+2 -> slot (I+2)&1 = SLOT.
#define KITER(I, SLOT, WAITIMM, DO_STAGE)                                      \
  {                                                                            \
    __builtin_amdgcn_s_waitcnt(WAITIMM);                                       \
    __builtin_amdgcn_sched_barrier(0);                                         \
    f32x4 xlc[4];                                                              \
    xlc[0] = xn[SLOT][0]; xlc[1] = xn[SLOT][1];                                \
    xlc[2] = xn[SLOT][2]; xlc[3] = xn[SLOT][3];                                \
    const u32* buf = mybuf + (SLOT) * 512;                                     \
    PackB bh0, bh1;                                                            \
    {                                                                          \
      const u32* row0 = buf + ln15 * 16;                                       \
      bh0.v = *(const u32x4*)(row0 + ((q ^ sw) * 4));                          \
      const u32* row1 = buf + (16 + ln15) * 16;                                \
      bh1.v = *(const u32x4*)(row1 + ((q ^ sw) * 4));                          \
    }                                                                          \
    asm volatile("s_waitcnt lgkmcnt(0)" ::: "memory");                         \
    __builtin_amdgcn_sched_barrier(0);                                         \
    if (DO_STAGE) {                                                            \
      stage2k(wt + (size_t)((t0 + (I) + 2) * 4 + nq) * 512,                    \
              mybuf + (SLOT) * 512, lane);                                     \
      const float* xp = xt + (size_t)(t0 + (I) + 2) * R_TOTAL + r0;            \
      xn[SLOT][0] = *(const f32x4*)(xp + 0 + q * 4);                           \
      xn[SLOT][1] = *(const f32x4*)(xp + 16 + q * 4);                          \
      xn[SLOT][2] = *(const f32x4*)(xp + 32 + q * 4);                          \
      xn[SLOT][3] = *(const f32x4*)(xp + 48 + q * 4);                          \
    }                                                                          \
    __builtin_amdgcn_sched_barrier(0);                                         \
    __builtin_amdgcn_s_setprio(1);                                             \
    _Pragma("unroll")                                                          \
    for (int f = 0; f < 4; ++f) {                                              \
      f32x4 Y = __builtin_amdgcn_mfma_f32_16x16x32_bf16(Ah[f].s, bh0.s, zero4, 0, 0, 0); \
      acc[f][0] += xlc[f] * Y;                                                 \
    }                                                                          \
    _Pragma("unroll")                                                          \
    for (int f = 0; f < 4; ++f) {                                              \
      f32x4 Y = __builtin_amdgcn_mfma_f32_16x16x32_bf16(Ah[f].s, bh1.s, zero4, 0, 0, 0); \
      acc[f][1] += xlc[f] * Y;                                                 \
    }                                                                          \
    __builtin_amdgcn_s_setprio(0);                                             \
    __builtin_amdgcn_sched_barrier(0);                                         \
  }

// ---------------- main layer kernel ----------------
template <int NT, bool RELU, bool STORE_X>
__global__ __launch_bounds__(512, 2) void layer_mfma(
    const float* __restrict__ xt,    // NT x R (transposed prev activation)
    const float* __restrict__ x0t,   // 32 x R
    const u32* __restrict__ wt,      // NT*4 quarter images (512 u32 each)
    const float* __restrict__ bias,  // 128
    float* __restrict__ xoutT,       // 128 x R (if STORE_X)
    float* __restrict__ osum)        // d_out + layer offset, stride 384
{
  constexpr int HT = NT / 2;
  static_assert((HT & 1) == 0 && HT >= 4, "pair-loop needs even HT >= 4");
  __shared__ u32 smem[16384];        // 64 KB: 8 waves x 2048 u32
                                     // (K-loop uses first 1024: 2 x 512 slots)

  const int tid = threadIdx.x;
  const int w = tid >> 6, lane = tid & 63;
  const int ln15 = lane & 15, q = lane >> 4;
  const int kh = w & 1, nq = w >> 1;
  const int r0 = blockIdx.x * 64;
  const int sw = ln15 & 3;           // 4-position XOR swizzle (2 KB image)
  u32* mybuf = smem + w * 2048;

  // ---- loop-invariant A fragments: RNE-rounded x0 rows (A[i=ln15][k=q*8+j])
  PackU Ah[4];
  #pragma unroll
  for (int f = 0; f < 4; ++f) {
    const int rbase = r0 + f * 16 + ln15;
    float e[8];
    #pragma unroll
    for (int j = 0; j < 8; ++j) e[j] = x0t[(size_t)(q * 8 + j) * R_TOTAL + rbase];
    #pragma unroll
    for (int jj = 0; jj < 4; ++jj)
      Ah[f].u[jj] = pack_rne(e[2 * jj], e[2 * jj + 1]);
  }

  f32x4 acc[4][2];
  #pragma unroll
  for (int f = 0; f < 4; ++f)
    #pragma unroll
    for (int c = 0; c < 2; ++c) acc[f][c] = f32x4{0.f, 0.f, 0.f, 0.f};
  const f32x4 zero4 = {0.f, 0.f, 0.f, 0.f};

  const int t0 = kh * HT;

  // ---- prologue: 2-deep prefetch (groups 0 and 1), issue order stage,xl ----
  f32x4 xn[2][4];
  stage2k(wt + (size_t)(t0 * 4 + nq) * 512, mybuf, lane);
  {
    const float* xp = xt + (size_t)t0 * R_TOTAL + r0;
    xn[0][0] = *(const f32x4*)(xp + 0 + q * 4);
    xn[0][1] = *(const f32x4*)(xp + 16 + q * 4);
    xn[0][2] = *(const f32x4*)(xp + 32 + q * 4);
    xn[0][3] = *(const f32x4*)(xp + 48 + q * 4);
  }
  stage2k(wt + (size_t)((t0 + 1) * 4 + nq) * 512, mybuf + 512, lane);
  {
    const float* xp = xt + (size_t)(t0 + 1) * R_TOTAL + r0;
    xn[1][0] = *(const f32x4*)(xp + 0 + q * 4);
    xn[1][1] = *(const f32x4*)(xp + 16 + q * 4);
    xn[1][2] = *(const f32x4*)(xp + 32 + q * 4);
    xn[1][3] = *(const f32x4*)(xp + 48 + q * 4);
  }
  __builtin_amdgcn_sched_barrier(0);

  // ---- steady state: every in-loop iter stages (i+2), waits vmcnt(6) ----
  for (int i = 0; i < HT - 2; i += 2) {
    KITER(i, 0, 0x0F76, 1);
    KITER(i + 1, 1, 0x0F76, 1);
  }
  // ---- peeled last pair: no staging; final iter drains to vmcnt(0) ----
  KITER(HT - 2, 0, 0x0F76, 0);
  KITER(HT - 1, 1, 0x0F70, 0);

  // ---------------- epilogue ----------------
  __syncthreads();                  // K-loop LDS regions now reusable
  if (kh == 1) {                    // dump partial acc into own region (8 KB)
    u32* reg = mybuf;
    #pragma unroll
    for (int f = 0; f < 4; ++f)
      #pragma unroll
      for (int c = 0; c < 2; ++c)
        *(f32x4*)(reg + ((size_t)(f * 2 + c) * 64 + lane) * 4) = acc[f][c];
  }
  __syncthreads();
  if (kh == 0) {
    const u32* reg = smem + (w + 1) * 2048;   // partner (kh=1, same nq)
    float bs[2];
    #pragma unroll
    for (int c = 0; c < 2; ++c) bs[c] = bias[nq * 32 + c * 16 + ln15];

    f32x4 vv[4][2];
    #pragma unroll
    for (int f = 0; f < 4; ++f) {
      #pragma unroll
      for (int c = 0; c < 2; ++c) {
        f32x4 part = *(const f32x4*)(reg + ((size_t)(f * 2 + c) * 64 + lane) * 4);
        f32x4 v = acc[f][c] + part;
        v.x += bs[c]; v.y += bs[c]; v.z += bs[c]; v.w += bs[c];
        if (RELU) {
          v.x = fmaxf(v.x, 0.f); v.y = fmaxf(v.y, 0.f);
          v.z = fmaxf(v.z, 0.f); v.w = fmaxf(v.w, 0.f);
        }
        vv[f][c] = v;
        float s = v.x + v.y + v.z + v.w;       // 4 rows of batch (r0>>4)+f
        s += __shfl_xor(s, 16, 64);
        s += __shfl_xor(s, 32, 64);
        if (q == 0)
          osum[(size_t)((r0 >> 4) + f) * 384 + nq * 32 + c * 16 + ln15] = s;
      }
    }

    if (STORE_X) {
      // transpose via own LDS region, then 64B-contiguous stores to XT.
      u32* myreg = mybuf;
      #pragma unroll
      for (int f = 0; f < 4; ++f)
        #pragma unroll
        for (int c = 0; c < 2; ++c)
          *(f32x4*)(myreg + ((size_t)(f * 2 + c) * 64 + lane) * 4) = vv[f][c];
      // element (r_local, lcol): frag (f=r>>4, c=lcol>>4), lane q=(r>>2)&3,
      // ln15=lcol&15, comp rr=r&3. Round (c,s): lane -> col=c*16+(lane>>2),
      // r_local = s*16 + (lane&3)*4.
      #pragma unroll
      for (int c = 0; c < 2; ++c) {
        #pragma unroll
        for (int s = 0; s < 4; ++s) {
          f32x4 vr = *(const f32x4*)(myreg +
              ((size_t)(s * 2 + c) * 64 + (lane & 3) * 16 + (lane >> 2)) * 4);
          const int col = nq * 32 + c * 16 + (lane >> 2);
          *(f32x4*)&xoutT[(size_t)col * R_TOTAL + r0 + s * 16 + (lane & 3) * 4] = vr;
        }
      }
    }
  }
}

extern "C" void kernel_launch(void* const* d_in, const int* in_sizes, int n_in,
                              void* d_out, int out_size, void* d_ws, size_t ws_size,
                              hipStream_t stream) {
  const float* in = (const float*)d_in[0];
  const float* W0 = (const float*)d_in[1];
  const float* b0 = (const float*)d_in[2];
  const float* W1 = (const float*)d_in[3];
  const float* b1 = (const float*)d_in[4];
  const float* W2 = (const float*)d_in[5];
  const float* b2 = (const float*)d_in[6];
  float* out = (float*)d_out;

  float* X0T = (float*)d_ws;                         // 32 x 16384   (2 MB)
  float* X1T = X0T + (size_t)32 * R_TOTAL;           // 128 x 16384  (8 MB)
  float* X2T = X1T + (size_t)128 * R_TOTAL;          // 128 x 16384  (8 MB)
  u32* Wt0 = (u32*)(X2T + (size_t)128 * R_TOTAL);    // 32*4*512 u32   (256 KB)
  u32* Wt1 = Wt0 + (size_t)32 * 4 * 512;             // 128*4*512 u32  (1 MB)
  u32* Wt2 = Wt1 + (size_t)128 * 4 * 512;            // 128*4*512 u32  (1 MB)
  // total ws: ~20.3 MB

  prep_all<<<1280, 256, 0, stream>>>(in, X0T, W0, Wt0, W1, Wt1, W2, Wt2);

  layer_mfma<32, true, true><<<256, 512, 0, stream>>>(X0T, X0T, Wt0, b0, X1T, out + 0);
  layer_mfma<128, true, true><<<256, 512, 0, stream>>>(X1T, X0T, Wt1, b1, X2T, out + 128);
  layer_mfma<128, false, false><<<256, 512, 0, stream>>>(X2T, X0T, Wt2, b2, nullptr, out + 256);
}